// Round 1
// baseline (4775.835 us; speedup 1.0000x reference)
//
#include <hip/hip_runtime.h>
#include <hip/hip_bf16.h>

// Problem constants (from reference)
#define NN 200000   // nodes
#define EE 200000   // edges per pre/suc scale
#define ELR 50000   // left/right edges
// D = 128, S = 6, L = 4

typedef __attribute__((ext_vector_type(8))) short bf16x8;
typedef __attribute__((ext_vector_type(4))) float f32x4;

__device__ __forceinline__ unsigned short f2bf(float f) {
    unsigned int u = __float_as_uint(f);
    u += 0x7FFFu + ((u >> 16) & 1u);     // RNE
    return (unsigned short)(u >> 16);
}
__device__ __forceinline__ float bf2f(unsigned short s) {
    return __uint_as_float(((unsigned int)s) << 16);
}
__device__ __forceinline__ bf16x8 ld8(const unsigned short* p) {
    return *reinterpret_cast<const bf16x8*>(p);
}

// ---------------------------------------------------------------------------
// Transpose+cast all [128,128] weight matrices to bf16, Wt[n][k] = W[k][n].
// Slots: 0 Wi2, 1 Ws2, 2+i W_ctr[i], 6+i*6+j W_pre[i][j], 30+i*6+j W_suc[i][j],
//        54+i W_left[i], 58+i W_right[i], 62+i W_ctr2[i].  66 slots total.
// ---------------------------------------------------------------------------
__global__ void k_wt(const float* __restrict__ Wi2, const float* __restrict__ Ws2,
                     const float* __restrict__ W_ctr, const float* __restrict__ W_pre,
                     const float* __restrict__ W_suc, const float* __restrict__ W_left,
                     const float* __restrict__ W_right, const float* __restrict__ W_ctr2,
                     unsigned short* __restrict__ Wt) {
    int slot = blockIdx.x;
    const float* src;
    if (slot == 0)        src = Wi2;
    else if (slot == 1)   src = Ws2;
    else if (slot < 6)    src = W_ctr   + (slot - 2)  * 16384;
    else if (slot < 30)   src = W_pre   + (slot - 6)  * 16384;
    else if (slot < 54)   src = W_suc   + (slot - 30) * 16384;
    else if (slot < 58)   src = W_left  + (slot - 54) * 16384;
    else if (slot < 62)   src = W_right + (slot - 58) * 16384;
    else                  src = W_ctr2  + (slot - 62) * 16384;
    unsigned short* dst = Wt + slot * 16384;
    for (int t = threadIdx.x; t < 16384; t += 256) {
        int n = t >> 7, k = t & 127;
        dst[t] = f2bf(src[k * 128 + n]);
    }
}

// ---------------------------------------------------------------------------
// H = relu(xy @ W1 + b1) as bf16 [N,128].  16 threads per node, 8 cols each.
// ---------------------------------------------------------------------------
__global__ void k_in(const float* __restrict__ xy, const float* __restrict__ W1,
                     const float* __restrict__ b1, unsigned short* __restrict__ H) {
    int t = threadIdx.x;
    int node = blockIdx.x * 16 + (t >> 4);
    int dc = (t & 15) * 8;
    float c0 = xy[node * 2], c1 = xy[node * 2 + 1];
    bf16x8 o;
#pragma unroll
    for (int j = 0; j < 8; j++) {
        int d = dc + j;
        float h = fmaf(c0, W1[d], fmaf(c1, W1[128 + d], b1[d]));
        o[j] = (short)f2bf(fmaxf(h, 0.f));
    }
    *reinterpret_cast<bf16x8*>(H + node * 128 + dc) = o;
}

// ---------------------------------------------------------------------------
// Dense GEMM: out[r][n] = sum_k feat[r][k] * W[k][n], W resident in VGPRs.
// Wave = 16-row chunks x full 128 cols.  K=128 fully unrolled (4 MFMA K-steps).
// MODE 0: store fp32 out (temp = feat @ W_ctr)
// MODE 1: GN(acc; g,b) -> store fp32 out                (input MLP part 1)
// MODE 2: GN + resF(fp32) -> relu -> out fp32 + outb bf16 (input MLP part 2)
// MODE 3: GN + resB(bf16) -> relu -> out fp32 + outb bf16 (fuse ctr2 stage)
// ---------------------------------------------------------------------------
template <int MODE>
__global__ __launch_bounds__(256, 2)
void k_gemm(const unsigned short* __restrict__ Bfeat, const unsigned short* __restrict__ Wt,
            float* __restrict__ out, const float* __restrict__ resF,
            const unsigned short* __restrict__ resB, unsigned short* __restrict__ outb,
            const float* __restrict__ g, const float* __restrict__ bb, int nrows) {
    int wid = threadIdx.x >> 6, lane = threadIdx.x & 63;
    int p = lane & 15, q = lane >> 4;

    // Resident weight B-fragments: B[k][n], lane holds col n = nf*16+p,
    // k = ks*32 + q*8 + j  ->  read from Wt[n][k] (transposed) = 16B contig.
    bf16x8 bw[4][8];
#pragma unroll
    for (int ks = 0; ks < 4; ks++)
#pragma unroll
        for (int nf = 0; nf < 8; nf++)
            bw[ks][nf] = ld8(Wt + (nf * 16 + p) * 128 + ks * 32 + q * 8);

    float gv[8], bv[8];
    if (MODE >= 1) {
#pragma unroll
        for (int nf = 0; nf < 8; nf++) { gv[nf] = g[nf * 16 + p]; bv[nf] = bb[nf * 16 + p]; }
    }

    int waveBase = (blockIdx.x * 4 + wid) * 128;   // 8 chunks of 16 rows per wave
#pragma unroll 1
    for (int c = 0; c < 8; c++) {
        int rb = waveBase + c * 16;
        if (rb >= nrows) break;
        int ra = rb + p; if (ra > nrows - 1) ra = nrows - 1;
        bf16x8 a[4];
#pragma unroll
        for (int ks = 0; ks < 4; ks++)
            a[ks] = ld8(Bfeat + ra * 128 + ks * 32 + q * 8);
        f32x4 acc[8];
#pragma unroll
        for (int nf = 0; nf < 8; nf++) acc[nf] = (f32x4){0.f, 0.f, 0.f, 0.f};
#pragma unroll
        for (int ks = 0; ks < 4; ks++)
#pragma unroll
            for (int nf = 0; nf < 8; nf++)
                acc[nf] = __builtin_amdgcn_mfma_f32_16x16x32_bf16(a[ks], bw[ks][nf], acc[nf], 0, 0, 0);

        if (MODE == 0) {
#pragma unroll
            for (int reg = 0; reg < 4; reg++) {
                int row = rb + q * 4 + reg;
                if (row < nrows) {
#pragma unroll
                    for (int nf = 0; nf < 8; nf++)
                        out[row * 128 + nf * 16 + p] = acc[nf][reg];
                }
            }
        } else {
            // Row stats: C row = q*4+reg (lane-local per reg), spread over p lanes.
            float s[4], s2[4];
#pragma unroll
            for (int reg = 0; reg < 4; reg++) {
                s[reg] = 0.f; s2[reg] = 0.f;
#pragma unroll
                for (int nf = 0; nf < 8; nf++) { float v = acc[nf][reg]; s[reg] += v; s2[reg] += v * v; }
            }
#pragma unroll
            for (int m = 1; m <= 8; m <<= 1) {
#pragma unroll
                for (int reg = 0; reg < 4; reg++) {
                    s[reg]  += __shfl_xor(s[reg],  m, 64);
                    s2[reg] += __shfl_xor(s2[reg], m, 64);
                }
            }
#pragma unroll
            for (int reg = 0; reg < 4; reg++) {
                int row = rb + q * 4 + reg;
                float mean = s[reg] * (1.f / 128.f);
                float var  = s2[reg] * (1.f / 128.f) - mean * mean;
                float rstd = rsqrtf(var + 1e-5f);
                if (row < nrows) {
#pragma unroll
                    for (int nf = 0; nf < 8; nf++) {
                        int col = nf * 16 + p;
                        float val = (acc[nf][reg] - mean) * rstd * gv[nf] + bv[nf];
                        if (MODE == 2) val += resF[row * 128 + col];
                        if (MODE == 3) val += bf2f(resB[row * 128 + col]);
                        if (MODE >= 2) val = fmaxf(val, 0.f);
                        out[row * 128 + col] = val;
                        if (MODE >= 2) outb[row * 128 + col] = f2bf(val);
                    }
                }
            }
        }
    }
}

// ---------------------------------------------------------------------------
// Edge scatter GEMM: temp[u[e]] += feat[v[e]] @ W_set, fused gather/MFMA/atomic.
// blockIdx.y = edge set (0-5 pre, 6-11 suc, 12 left, 13 right).
// ---------------------------------------------------------------------------
__global__ __launch_bounds__(256, 2)
void k_edge(const unsigned short* __restrict__ featb, float* __restrict__ temp,
            const int* __restrict__ pre_u, const int* __restrict__ pre_v,
            const int* __restrict__ suc_u, const int* __restrict__ suc_v,
            const int* __restrict__ left_u, const int* __restrict__ left_v,
            const int* __restrict__ right_u, const int* __restrict__ right_v,
            const unsigned short* __restrict__ Wt, int iter) {
    int s = blockIdx.y;
    const int *up, *vp; int ne, slot;
    if (s < 6)       { up = pre_u + s * EE;        vp = pre_v + s * EE;        ne = EE;  slot = 6 + iter * 6 + s; }
    else if (s < 12) { int j = s - 6; up = suc_u + j * EE; vp = suc_v + j * EE; ne = EE; slot = 30 + iter * 6 + j; }
    else if (s == 12){ up = left_u;  vp = left_v;  ne = ELR; slot = 54 + iter; }
    else             { up = right_u; vp = right_v; ne = ELR; slot = 58 + iter; }

    int blockBase = blockIdx.x * 512;
    if (blockBase >= ne) return;
    const unsigned short* W = Wt + slot * 16384;

    int wid = threadIdx.x >> 6, lane = threadIdx.x & 63;
    int p = lane & 15, q = lane >> 4;

    bf16x8 bw[4][8];
#pragma unroll
    for (int ks = 0; ks < 4; ks++)
#pragma unroll
        for (int nf = 0; nf < 8; nf++)
            bw[ks][nf] = ld8(W + (nf * 16 + p) * 128 + ks * 32 + q * 8);

    int waveBase = blockBase + wid * 128;
    if (waveBase >= ne) return;

    auto loadA = [&](int eb, bf16x8* a) {
        int ev = eb + p; if (ev > ne - 1) ev = ne - 1;
        int vrow = vp[ev];
#pragma unroll
        for (int ks = 0; ks < 4; ks++)
            a[ks] = ld8(featb + vrow * 128 + ks * 32 + q * 8);
    };

    bf16x8 aCur[4];
    loadA(waveBase, aCur);
#pragma unroll 1
    for (int c = 0; c < 8; c++) {
        int eb = waveBase + c * 16;
        if (eb >= ne) break;
        bf16x8 aNext[4];
        int ebn = eb + 16;
        if (ebn < ne) loadA(ebn, aNext);   // prefetch next chunk's gathered rows

        f32x4 acc[8];
#pragma unroll
        for (int nf = 0; nf < 8; nf++) acc[nf] = (f32x4){0.f, 0.f, 0.f, 0.f};
#pragma unroll
        for (int ks = 0; ks < 4; ks++)
#pragma unroll
            for (int nf = 0; nf < 8; nf++)
                acc[nf] = __builtin_amdgcn_mfma_f32_16x16x32_bf16(aCur[ks], bw[ks][nf], acc[nf], 0, 0, 0);

#pragma unroll
        for (int reg = 0; reg < 4; reg++) {
            int er = eb + q * 4 + reg;      // edge for this output row
            if (er < ne) {
                int urow = up[er];
#pragma unroll
                for (int nf = 0; nf < 8; nf++)
                    unsafeAtomicAdd(&temp[urow * 128 + nf * 16 + p], acc[nf][reg]);
            }
        }
#pragma unroll
        for (int ks = 0; ks < 4; ks++) aCur[ks] = aNext[ks];
    }
}

// ---------------------------------------------------------------------------
// featm = bf16( relu( GN(temp; g,b) ) ).  One wave per row.
// ---------------------------------------------------------------------------
__global__ void k_norm(const float* __restrict__ temp, const float* __restrict__ g,
                       const float* __restrict__ b, unsigned short* __restrict__ featm) {
    int wid = threadIdx.x >> 6, lane = threadIdx.x & 63;
    int row = blockIdx.x * 4 + wid;
    if (row >= NN) return;
    float2 x = *reinterpret_cast<const float2*>(temp + row * 128 + lane * 2);
    float s = x.x + x.y, s2 = x.x * x.x + x.y * x.y;
#pragma unroll
    for (int m = 1; m <= 32; m <<= 1) { s += __shfl_xor(s, m, 64); s2 += __shfl_xor(s2, m, 64); }
    float mean = s * (1.f / 128.f);
    float var  = s2 * (1.f / 128.f) - mean * mean;
    float rstd = rsqrtf(var + 1e-5f);
    float r0 = fmaxf((x.x - mean) * rstd * g[lane * 2]     + b[lane * 2],     0.f);
    float r1 = fmaxf((x.y - mean) * rstd * g[lane * 2 + 1] + b[lane * 2 + 1], 0.f);
    unsigned int packed = (unsigned int)f2bf(r0) | ((unsigned int)f2bf(r1) << 16);
    *reinterpret_cast<unsigned int*>(featm + row * 128 + lane * 2) = packed;
}

// ---------------------------------------------------------------------------
extern "C" void kernel_launch(void* const* d_in, const int* in_sizes, int n_in,
                              void* d_out, int out_size, void* d_ws, size_t ws_size,
                              hipStream_t stream) {
    (void)in_sizes; (void)n_in; (void)out_size; (void)ws_size;
    const float* ctrs   = (const float*)d_in[0];
    const float* feats  = (const float*)d_in[1];
    const float* Wi1    = (const float*)d_in[2];
    const float* bi1    = (const float*)d_in[3];
    const float* Wi2    = (const float*)d_in[4];
    const float* gi     = (const float*)d_in[5];
    const float* bi     = (const float*)d_in[6];
    const float* Ws1    = (const float*)d_in[7];
    const float* bs1    = (const float*)d_in[8];
    const float* Ws2    = (const float*)d_in[9];
    const float* gs     = (const float*)d_in[10];
    const float* bs     = (const float*)d_in[11];
    const float* W_ctr  = (const float*)d_in[12];
    const float* W_pre  = (const float*)d_in[13];
    const float* W_suc  = (const float*)d_in[14];
    const float* W_left = (const float*)d_in[15];
    const float* W_right= (const float*)d_in[16];
    const float* norm_g = (const float*)d_in[17];
    const float* norm_b = (const float*)d_in[18];
    const float* W_ctr2 = (const float*)d_in[19];
    const float* ctr2_g = (const float*)d_in[20];
    const float* ctr2_b = (const float*)d_in[21];
    const int* pre_u  = (const int*)d_in[22];
    const int* pre_v  = (const int*)d_in[23];
    const int* suc_u  = (const int*)d_in[24];
    const int* suc_v  = (const int*)d_in[25];
    const int* left_u = (const int*)d_in[26];
    const int* left_v = (const int*)d_in[27];
    const int* right_u= (const int*)d_in[28];
    const int* right_v= (const int*)d_in[29];

    // Workspace: Wt (66*128*128 bf16 = 2,162,688 B) | featb (51.2 MB) | featm (51.2 MB)
    char* ws = (char*)d_ws;
    unsigned short* Wt    = (unsigned short*)ws;
    unsigned short* featb = (unsigned short*)(ws + 2162688);
    unsigned short* featm = (unsigned short*)(ws + 2162688 + 51200000);
    float* temp = (float*)d_out;   // temp aliases d_out (dead between stages)
    float* outF = (float*)d_out;

    const int GEMM_GRID = (NN + 511) / 512;   // 391

    k_wt<<<66, 256, 0, stream>>>(Wi2, Ws2, W_ctr, W_pre, W_suc, W_left, W_right, W_ctr2, Wt);

    // Input stage: feat = relu(GN(relu(ctrs@Wi1+bi1)@Wi2) + GN(relu(feats@Ws1+bs1)@Ws2))
    k_in<<<NN / 16, 256, 0, stream>>>(ctrs, Wi1, bi1, featm);
    k_gemm<1><<<GEMM_GRID, 256, 0, stream>>>(featm, Wt + 0 * 16384, outF, nullptr, nullptr, nullptr, gi, bi, NN);
    k_in<<<NN / 16, 256, 0, stream>>>(feats, Ws1, bs1, featm);
    k_gemm<2><<<GEMM_GRID, 256, 0, stream>>>(featm, Wt + 1 * 16384, outF, outF, nullptr, featb, gs, bs, NN);

    for (int i = 0; i < 4; i++) {
        // temp = feat @ W_ctr[i]
        k_gemm<0><<<GEMM_GRID, 256, 0, stream>>>(featb, Wt + (2 + i) * 16384, temp,
                                                 nullptr, nullptr, nullptr, nullptr, nullptr, NN);
        // temp[u] += feat[v] @ W_set  for all 14 edge sets
        dim3 ge(GEMM_GRID, 14);
        k_edge<<<ge, 256, 0, stream>>>(featb, temp, pre_u, pre_v, suc_u, suc_v,
                                       left_u, left_v, right_u, right_v, Wt, i);
        // featm = relu(GN(temp))
        k_norm<<<(NN + 3) / 4, 256, 0, stream>>>(temp, norm_g + i * 128, norm_b + i * 128, featm);
        // feat = relu(GN(featm @ W_ctr2[i]) + res);  res carried as bf16 in featb
        k_gemm<3><<<GEMM_GRID, 256, 0, stream>>>(featm, Wt + (62 + i) * 16384, outF,
                                                 nullptr, featb, featb,
                                                 ctr2_g + i * 128, ctr2_b + i * 128, NN);
    }
}

// Round 2
// 2388.384 us; speedup vs baseline: 1.9996x; 1.9996x over previous
//
#include <hip/hip_runtime.h>
#include <hip/hip_bf16.h>

// Problem constants (from reference)
#define NN 200000   // nodes
#define EE 200000   // edges per pre/suc scale
#define ELR 50000   // left/right edges
#define TOTE 2500000        // 12*EE + 2*ELR
#define MTOT 2800000        // 14 * NN  (CSR key space)
// D = 128, S = 6, L = 4

typedef __attribute__((ext_vector_type(8))) short bf16x8;
typedef __attribute__((ext_vector_type(4))) float f32x4;

__device__ __forceinline__ unsigned short f2bf(float f) {
    unsigned int u = __float_as_uint(f);
    u += 0x7FFFu + ((u >> 16) & 1u);     // RNE
    return (unsigned short)(u >> 16);
}
__device__ __forceinline__ float bf2f(unsigned short s) {
    return __uint_as_float(((unsigned int)s) << 16);
}
__device__ __forceinline__ bf16x8 ld8(const unsigned short* p) {
    return *reinterpret_cast<const bf16x8*>(p);
}

// ---------------------------------------------------------------------------
// Cast all [128,128] weights to bf16 in MFMA B-FRAGMENT ORDER:
// short index (slot, (ks*8+nf)*64 + lane, j8) holds W[ks*32+(lane>>4)*8+j8][nf*16+(lane&15)].
// A resident/LDS B-frag load is then a contiguous 16B read at ((ks*8+nf)*64+lane)*8.
// Slots: 0 Wi2, 1 Ws2, 2+i W_ctr[i], 6+i*6+j W_pre[i][j], 30+i*6+j W_suc[i][j],
//        54+i W_left[i], 58+i W_right[i], 62+i W_ctr2[i].  66 slots.
// ---------------------------------------------------------------------------
__global__ void k_wt(const float* __restrict__ Wi2, const float* __restrict__ Ws2,
                     const float* __restrict__ W_ctr, const float* __restrict__ W_pre,
                     const float* __restrict__ W_suc, const float* __restrict__ W_left,
                     const float* __restrict__ W_right, const float* __restrict__ W_ctr2,
                     unsigned short* __restrict__ Wt) {
    int slot = blockIdx.x;
    const float* src;
    if (slot == 0)        src = Wi2;
    else if (slot == 1)   src = Ws2;
    else if (slot < 6)    src = W_ctr   + (slot - 2)  * 16384;
    else if (slot < 30)   src = W_pre   + (slot - 6)  * 16384;
    else if (slot < 54)   src = W_suc   + (slot - 30) * 16384;
    else if (slot < 58)   src = W_left  + (slot - 54) * 16384;
    else if (slot < 62)   src = W_right + (slot - 58) * 16384;
    else                  src = W_ctr2  + (slot - 62) * 16384;
    unsigned short* dst = Wt + slot * 16384;
    for (int d = threadIdx.x; d < 2048; d += 256) {   // d = octet index (f*64 + lane)
        int f = d >> 6, l = d & 63;
        int ks = f >> 3, nf = f & 7;
        int k0 = ks * 32 + (l >> 4) * 8, n = nf * 16 + (l & 15);
        bf16x8 o;
#pragma unroll
        for (int j8 = 0; j8 < 8; j8++) o[j8] = (short)f2bf(src[(k0 + j8) * 128 + n]);
        *reinterpret_cast<bf16x8*>(dst + d * 8) = o;
    }
}

// ---------------------------------------------------------------------------
// H = relu(xy @ W1 + b1) as bf16 [N,128].  16 threads per node, 8 cols each.
// ---------------------------------------------------------------------------
__global__ void k_in(const float* __restrict__ xy, const float* __restrict__ W1,
                     const float* __restrict__ b1, unsigned short* __restrict__ H) {
    int t = threadIdx.x;
    int node = blockIdx.x * 16 + (t >> 4);
    int dc = (t & 15) * 8;
    float c0 = xy[node * 2], c1 = xy[node * 2 + 1];
    bf16x8 o;
#pragma unroll
    for (int j = 0; j < 8; j++) {
        int d = dc + j;
        float h = fmaf(c0, W1[d], fmaf(c1, W1[128 + d], b1[d]));
        o[j] = (short)f2bf(fmaxf(h, 0.f));
    }
    *reinterpret_cast<bf16x8*>(H + node * 128 + dc) = o;
}

// ---------------------------------------------------------------------------
// Dense GEMM with W resident in VGPRs (fragment-ordered Wt, one slot).
// MODE 1: GN(acc; g,b) -> store fp32 out                    (input MLP part 1)
// MODE 2: GN + resF(fp32) -> relu -> outb bf16 (+out if !=null)
// MODE 3: GN + resB(bf16) -> relu -> outb bf16 (+out if !=null)
// ---------------------------------------------------------------------------
template <int MODE>
__global__ __launch_bounds__(256, 2)
void k_gemm(const unsigned short* __restrict__ Bfeat, const unsigned short* __restrict__ Wt,
            float* __restrict__ out, const float* __restrict__ resF,
            const unsigned short* __restrict__ resB, unsigned short* __restrict__ outb,
            const float* __restrict__ g, const float* __restrict__ bb, int nrows) {
    int wid = threadIdx.x >> 6, lane = threadIdx.x & 63;
    int p = lane & 15, q = lane >> 4;

    bf16x8 bw[4][8];
#pragma unroll
    for (int ks = 0; ks < 4; ks++)
#pragma unroll
        for (int nf = 0; nf < 8; nf++)
            bw[ks][nf] = ld8(Wt + ((ks * 8 + nf) * 64 + lane) * 8);

    float gv[8], bv[8];
#pragma unroll
    for (int nf = 0; nf < 8; nf++) { gv[nf] = g[nf * 16 + p]; bv[nf] = bb[nf * 16 + p]; }

    int waveBase = (blockIdx.x * 4 + wid) * 128;   // 8 chunks of 16 rows per wave
#pragma unroll 1
    for (int c = 0; c < 8; c++) {
        int rb = waveBase + c * 16;
        if (rb >= nrows) break;
        int ra = rb + p; if (ra > nrows - 1) ra = nrows - 1;
        bf16x8 a[4];
#pragma unroll
        for (int ks = 0; ks < 4; ks++)
            a[ks] = ld8(Bfeat + ra * 128 + ks * 32 + q * 8);
        f32x4 acc[8];
#pragma unroll
        for (int nf = 0; nf < 8; nf++) acc[nf] = (f32x4){0.f, 0.f, 0.f, 0.f};
#pragma unroll
        for (int ks = 0; ks < 4; ks++)
#pragma unroll
            for (int nf = 0; nf < 8; nf++)
                acc[nf] = __builtin_amdgcn_mfma_f32_16x16x32_bf16(a[ks], bw[ks][nf], acc[nf], 0, 0, 0);

        float s[4], s2[4];
#pragma unroll
        for (int reg = 0; reg < 4; reg++) {
            s[reg] = 0.f; s2[reg] = 0.f;
#pragma unroll
            for (int nf = 0; nf < 8; nf++) { float v = acc[nf][reg]; s[reg] += v; s2[reg] += v * v; }
        }
#pragma unroll
        for (int m = 1; m <= 8; m <<= 1) {
#pragma unroll
            for (int reg = 0; reg < 4; reg++) {
                s[reg]  += __shfl_xor(s[reg],  m, 64);
                s2[reg] += __shfl_xor(s2[reg], m, 64);
            }
        }
#pragma unroll
        for (int reg = 0; reg < 4; reg++) {
            int row = rb + q * 4 + reg;
            float mean = s[reg] * (1.f / 128.f);
            float var  = s2[reg] * (1.f / 128.f) - mean * mean;
            float rstd = rsqrtf(var + 1e-5f);
            if (row < nrows) {
#pragma unroll
                for (int nf = 0; nf < 8; nf++) {
                    int col = nf * 16 + p;
                    float val = (acc[nf][reg] - mean) * rstd * gv[nf] + bv[nf];
                    if (MODE == 2) val += resF[row * 128 + col];
                    if (MODE == 3) val += bf2f(resB[row * 128 + col]);
                    if (MODE >= 2) val = fmaxf(val, 0.f);
                    if (MODE == 1 || out != nullptr) out[row * 128 + col] = val;
                    if (MODE >= 2) outb[row * 128 + col] = f2bf(val);
                }
            }
        }
    }
}

// ---------------------------------------------------------------------------
// CSR build: histogram -> scan -> scatter.  Combined key = set*NN + u, 14 sets.
// ---------------------------------------------------------------------------
__device__ __forceinline__ void edge_map(int t, const int* pre, const int* suc,
                                         const int* lft, const int* rgt, int& set, int& val) {
    if (t < 1200000)      { set = t / 200000;                 val = pre[t]; }
    else if (t < 2400000) { int r = t - 1200000; set = 6 + r / 200000; val = suc[r]; }
    else if (t < 2450000) { int r = t - 2400000; set = 12;    val = lft[r]; }
    else                  { int r = t - 2450000; set = 13;    val = rgt[r]; }
}

__global__ void k_hist(const int* __restrict__ pre_u, const int* __restrict__ suc_u,
                       const int* __restrict__ left_u, const int* __restrict__ right_u,
                       int* __restrict__ cnt) {
    int t = blockIdx.x * 256 + threadIdx.x;
    if (t >= TOTE) return;
    int set, u;
    edge_map(t, pre_u, suc_u, left_u, right_u, set, u);
    atomicAdd(&cnt[set * NN + u], 1);
}

__global__ void k_scan1(const int* __restrict__ cnt, int* __restrict__ bsum) {
    __shared__ int sh[256];
    int t = threadIdx.x;
    int base = blockIdx.x * 2048 + t * 8;
    int s = 0;
#pragma unroll
    for (int k = 0; k < 8; k++) { int i = base + k; s += (i < MTOT) ? cnt[i] : 0; }
    sh[t] = s; __syncthreads();
    for (int st = 128; st > 0; st >>= 1) {
        if (t < st) sh[t] += sh[t + st];
        __syncthreads();
    }
    if (t == 0) bsum[blockIdx.x] = sh[0];
}

__global__ void k_scan2(int* __restrict__ bsum, int nb) {   // 1 block, 64 threads
    int lane = threadIdx.x;
    int run = 0;
    for (int base = 0; base < nb; base += 64) {
        int i = base + lane;
        int v = (i < nb) ? bsum[i] : 0;
        int x = v;
#pragma unroll
        for (int d = 1; d < 64; d <<= 1) { int y = __shfl_up(x, d, 64); if (lane >= d) x += y; }
        int excl = x - v + run;
        if (i < nb) bsum[i] = excl;
        run += __shfl(x, 63, 64);
    }
}

__global__ void k_scan3(const int* __restrict__ cnt, const int* __restrict__ bsum,
                        int* __restrict__ off, int* __restrict__ cursor) {
    __shared__ int sh[256];
    int t = threadIdx.x;
    int base = blockIdx.x * 2048 + t * 8;
    int c[8]; int ts = 0;
#pragma unroll
    for (int k = 0; k < 8; k++) { int i = base + k; c[k] = (i < MTOT) ? cnt[i] : 0; ts += c[k]; }
    sh[t] = ts; __syncthreads();
    for (int d = 1; d < 256; d <<= 1) {
        int y = (t >= d) ? sh[t - d] : 0;
        __syncthreads();
        sh[t] += y;
        __syncthreads();
    }
    int run = sh[t] - ts + bsum[blockIdx.x];
#pragma unroll
    for (int k = 0; k < 8; k++) {
        int i = base + k;
        if (i < MTOT) { off[i] = run; cursor[i] = run; run += c[k]; }
    }
    if (blockIdx.x == 0 && t == 0) off[MTOT] = TOTE;
}

__global__ void k_scatter(const int* __restrict__ pre_u, const int* __restrict__ pre_v,
                          const int* __restrict__ suc_u, const int* __restrict__ suc_v,
                          const int* __restrict__ left_u, const int* __restrict__ left_v,
                          const int* __restrict__ right_u, const int* __restrict__ right_v,
                          int* __restrict__ cursor, int* __restrict__ eidx) {
    int t = blockIdx.x * 256 + threadIdx.x;
    if (t >= TOTE) return;
    int set, u, setv, v;
    edge_map(t, pre_u, suc_u, left_u, right_u, set, u);
    edge_map(t, pre_v, suc_v, left_v, right_v, setv, v);
    int pos = atomicAdd(&cursor[set * NN + u], 1);
    eidx[pos] = v;
}

// ---------------------------------------------------------------------------
// Fused fuse-iteration kernel (pull-based, no atomics):
//   featm[u] = bf16( relu( GN( feat[u]@Wc + Sum_j (Sum_{e in CSR_j[u]} feat[v_e]) @ W_j ) ) )
// Block = 4 waves x 16 rows = 64 rows.  Per set: stage 32KB W to LDS (fragment
// order, contiguous ds_read_b128 = conflict-free), gather+sum A rows in fp32,
// 32 MFMAs into a persistent accumulator.  GN+relu epilogue in-wave.
// ---------------------------------------------------------------------------
__global__ __launch_bounds__(256, 2)
void k_fuse(const unsigned short* __restrict__ featb, const int* __restrict__ off,
            const int* __restrict__ eidx, const unsigned short* __restrict__ Wt,
            const float* __restrict__ g, const float* __restrict__ b,
            unsigned short* __restrict__ featm, int iter) {
    __shared__ __align__(16) unsigned short wlds[16384];
    int tid = threadIdx.x, wid = tid >> 6, lane = tid & 63;
    int p = lane & 15, q = lane >> 4;
    int rb = blockIdx.x * 64 + wid * 16;

    f32x4 acc[8];
#pragma unroll
    for (int nf = 0; nf < 8; nf++) acc[nf] = (f32x4){0.f, 0.f, 0.f, 0.f};
    float gv[8], bv[8];
#pragma unroll
    for (int nf = 0; nf < 8; nf++) { gv[nf] = g[nf * 16 + p]; bv[nf] = b[nf * 16 + p]; }

#pragma unroll 1
    for (int j = 0; j < 15; j++) {
        int slot;
        if (j == 0)       slot = 2 + iter;
        else if (j <= 6)  slot = 6 + iter * 6 + (j - 1);
        else if (j <= 12) slot = 30 + iter * 6 + (j - 7);
        else if (j == 13) slot = 54 + iter;
        else              slot = 58 + iter;
        const unsigned short* wsrc = Wt + slot * 16384;

        __syncthreads();   // previous MFMA reads done before overwriting wlds
#pragma unroll
        for (int k = 0; k < 8; k++)
            *reinterpret_cast<bf16x8*>(wlds + k * 2048 + tid * 8) = ld8(wsrc + k * 2048 + tid * 8);

        bf16x8 af[4];
        if (j == 0) {
#pragma unroll
            for (int ks = 0; ks < 4; ks++)
                af[ks] = ld8(featb + (rb + p) * 128 + ks * 32 + q * 8);
        } else {
            int key = (j - 1) * NN + rb + p;
            int s0 = off[key], e0 = off[key + 1];
            float sa[4][8];
#pragma unroll
            for (int ks = 0; ks < 4; ks++)
#pragma unroll
                for (int k2 = 0; k2 < 8; k2++) sa[ks][k2] = 0.f;
            for (int t2 = s0; t2 < e0; t2++) {
                int v = eidx[t2];
#pragma unroll
                for (int ks = 0; ks < 4; ks++) {
                    bf16x8 r = ld8(featb + v * 128 + ks * 32 + q * 8);
#pragma unroll
                    for (int k2 = 0; k2 < 8; k2++) sa[ks][k2] += bf2f((unsigned short)r[k2]);
                }
            }
#pragma unroll
            for (int ks = 0; ks < 4; ks++)
#pragma unroll
                for (int k2 = 0; k2 < 8; k2++) af[ks][k2] = (short)f2bf(sa[ks][k2]);
        }

        __syncthreads();   // wlds staged
#pragma unroll
        for (int ks = 0; ks < 4; ks++)
#pragma unroll
            for (int nf = 0; nf < 8; nf++) {
                bf16x8 bwf = *reinterpret_cast<const bf16x8*>(wlds + ((ks * 8 + nf) * 64 + lane) * 8);
                acc[nf] = __builtin_amdgcn_mfma_f32_16x16x32_bf16(af[ks], bwf, acc[nf], 0, 0, 0);
            }
    }

    // GN + relu -> featm (bf16)
    float s[4], s2[4];
#pragma unroll
    for (int reg = 0; reg < 4; reg++) {
        s[reg] = 0.f; s2[reg] = 0.f;
#pragma unroll
        for (int nf = 0; nf < 8; nf++) { float v = acc[nf][reg]; s[reg] += v; s2[reg] += v * v; }
    }
#pragma unroll
    for (int m = 1; m <= 8; m <<= 1) {
#pragma unroll
        for (int reg = 0; reg < 4; reg++) {
            s[reg]  += __shfl_xor(s[reg],  m, 64);
            s2[reg] += __shfl_xor(s2[reg], m, 64);
        }
    }
#pragma unroll
    for (int reg = 0; reg < 4; reg++) {
        int row = rb + q * 4 + reg;
        float mean = s[reg] * (1.f / 128.f);
        float var  = s2[reg] * (1.f / 128.f) - mean * mean;
        float rstd = rsqrtf(var + 1e-5f);
#pragma unroll
        for (int nf = 0; nf < 8; nf++) {
            int col = nf * 16 + p;
            float val = fmaxf((acc[nf][reg] - mean) * rstd * gv[nf] + bv[nf], 0.f);
            featm[row * 128 + col] = f2bf(val);
        }
    }
}

// ---------------------------------------------------------------------------
extern "C" void kernel_launch(void* const* d_in, const int* in_sizes, int n_in,
                              void* d_out, int out_size, void* d_ws, size_t ws_size,
                              hipStream_t stream) {
    (void)in_sizes; (void)n_in; (void)out_size; (void)ws_size;
    const float* ctrs   = (const float*)d_in[0];
    const float* feats  = (const float*)d_in[1];
    const float* Wi1    = (const float*)d_in[2];
    const float* bi1    = (const float*)d_in[3];
    const float* Wi2    = (const float*)d_in[4];
    const float* gi     = (const float*)d_in[5];
    const float* bi     = (const float*)d_in[6];
    const float* Ws1    = (const float*)d_in[7];
    const float* bs1    = (const float*)d_in[8];
    const float* Ws2    = (const float*)d_in[9];
    const float* gs     = (const float*)d_in[10];
    const float* bs     = (const float*)d_in[11];
    const float* W_ctr  = (const float*)d_in[12];
    const float* W_pre  = (const float*)d_in[13];
    const float* W_suc  = (const float*)d_in[14];
    const float* W_left = (const float*)d_in[15];
    const float* W_right= (const float*)d_in[16];
    const float* norm_g = (const float*)d_in[17];
    const float* norm_b = (const float*)d_in[18];
    const float* W_ctr2 = (const float*)d_in[19];
    const float* ctr2_g = (const float*)d_in[20];
    const float* ctr2_b = (const float*)d_in[21];
    const int* pre_u  = (const int*)d_in[22];
    const int* pre_v  = (const int*)d_in[23];
    const int* suc_u  = (const int*)d_in[24];
    const int* suc_v  = (const int*)d_in[25];
    const int* left_u = (const int*)d_in[26];
    const int* left_v = (const int*)d_in[27];
    const int* right_u= (const int*)d_in[28];
    const int* right_v= (const int*)d_in[29];

    // ws: Wt (2,162,688 B) | featb (51.2 MB) | featm (51.2 MB)  = 104.56 MB
    char* ws = (char*)d_ws;
    unsigned short* Wt    = (unsigned short*)ws;
    unsigned short* featb = (unsigned short*)(ws + 2162688);
    unsigned short* featm = (unsigned short*)(ws + 2162688 + 51200000);

    // d_out doubles as CSR scratch until the final output write (iter 3 GEMM):
    //   off/cnt: [0, 11,200,016) | cursor: [.., 22,400,016) | eidx: [.., 32,400,016) | bsum
    char* ob = (char*)d_out;
    int* cnt    = (int*)ob;                 // aliased: histogram then row offsets
    int* off    = (int*)ob;
    int* cursor = (int*)(ob + 11200016);
    int* eidx   = (int*)(ob + 22400016);
    int* bsum   = (int*)(ob + 32400016);
    float* outF = (float*)d_out;

    const int GEMM_GRID = (NN + 511) / 512;       // 391
    const int NB_SCAN   = (MTOT + 2047) / 2048;   // 1368

    k_wt<<<66, 256, 0, stream>>>(Wi2, Ws2, W_ctr, W_pre, W_suc, W_left, W_right, W_ctr2, Wt);

    // Input stage (uses d_out as fp32 temp BEFORE the CSR build claims it)
    k_in<<<NN / 16, 256, 0, stream>>>(ctrs, Wi1, bi1, featm);
    k_gemm<1><<<GEMM_GRID, 256, 0, stream>>>(featm, Wt + 0 * 16384, outF, nullptr, nullptr, nullptr, gi, bi, NN);
    k_in<<<NN / 16, 256, 0, stream>>>(feats, Ws1, bs1, featm);
    k_gemm<2><<<GEMM_GRID, 256, 0, stream>>>(featm, Wt + 1 * 16384, nullptr, outF, nullptr, featb, gs, bs, NN);

    // CSR build (one-time, in d_out scratch)
    hipMemsetAsync(cnt, 0, (MTOT + 1) * sizeof(int), stream);
    k_hist<<<(TOTE + 255) / 256, 256, 0, stream>>>(pre_u, suc_u, left_u, right_u, cnt);
    k_scan1<<<NB_SCAN, 256, 0, stream>>>(cnt, bsum);
    k_scan2<<<1, 64, 0, stream>>>(bsum, NB_SCAN);
    k_scan3<<<NB_SCAN, 256, 0, stream>>>(cnt, bsum, off, cursor);
    k_scatter<<<(TOTE + 255) / 256, 256, 0, stream>>>(pre_u, pre_v, suc_u, suc_v,
                                                      left_u, left_v, right_u, right_v,
                                                      cursor, eidx);

    for (int i = 0; i < 4; i++) {
        k_fuse<<<NN / 64, 256, 0, stream>>>(featb, off, eidx, Wt,
                                            norm_g + i * 128, norm_b + i * 128, featm, i);
        // feat = relu(GN(featm @ W_ctr2[i]) + res); fp32 out only on last iter
        k_gemm<3><<<GEMM_GRID, 256, 0, stream>>>(featm, Wt + (62 + i) * 16384,
                                                 (i == 3) ? outF : nullptr,
                                                 nullptr, featb, featb,
                                                 ctr2_g + i * 128, ctr2_b + i * 128, NN);
    }
}